// Round 7
// baseline (340.866 us; speedup 1.0000x reference)
//
#include <hip/hip_runtime.h>
#include <hip/hip_bf16.h>
#include <cstdint>

#define B_ 2
#define S_ 4096
#define E_ 768
#define H_ 12
#define D_ 64

typedef __bf16 bf16x8 __attribute__((ext_vector_type(8)));
typedef __bf16 bf16x4 __attribute__((ext_vector_type(4)));
typedef float f32x4 __attribute__((ext_vector_type(4)));
typedef unsigned short ushort8 __attribute__((ext_vector_type(8)));
typedef unsigned short ushort4v __attribute__((ext_vector_type(4)));

static __device__ __forceinline__ unsigned short f2bf(float f) {
    union { float f; uint32_t u; } v; v.f = f;
    uint32_t u = v.u;
    u += 0x7FFFu + ((u >> 16) & 1u);
    return (unsigned short)(u >> 16);
}

static __device__ __forceinline__ void gl_lds16(const unsigned short* g, unsigned short* l) {
    __builtin_amdgcn_global_load_lds((const __attribute__((address_space(1))) unsigned int*)g,
                                     (__attribute__((address_space(3))) unsigned int*)l, 16, 0, 0);
}

// ---------------- convert hidden_states fp32 -> bf16 ----------------
__global__ void cvt_x(const float* __restrict__ x, unsigned short* __restrict__ xb, int n4) {
    int i = blockIdx.x * blockDim.x + threadIdx.x;
    int stride = gridDim.x * blockDim.x;
    for (; i < n4; i += stride) {
        float4 f = ((const float4*)x)[i];
        ushort4v o;
        o.x = f2bf(f.x); o.y = f2bf(f.y); o.z = f2bf(f.z); o.w = f2bf(f.w);
        ((ushort4v*)xb)[i] = o;
    }
}

// ---------------- convert + transpose weights: WT[n][k] = W[k][n], bf16 ----------------
__global__ void cvt_w(const float* __restrict__ Wq, const float* __restrict__ Wk,
                      const float* __restrict__ Wv, unsigned short* __restrict__ wt) {
    __shared__ float tl[32][33];
    int wsel = blockIdx.z;
    const float* src = wsel == 0 ? Wq : (wsel == 1 ? Wk : Wv);
    int tx = threadIdx.x, ty = threadIdx.y;
    int n0 = blockIdx.x * 32, k0 = blockIdx.y * 32;
    for (int i = 0; i < 4; i++) {
        int k = k0 + ty + i * 8;
        tl[ty + i * 8][tx] = src[(size_t)k * E_ + n0 + tx];
    }
    __syncthreads();
    unsigned short* dst = wt + (size_t)wsel * E_ * E_;
    for (int i = 0; i < 4; i++) {
        int n = n0 + ty + i * 8;
        dst[(size_t)n * E_ + k0 + tx] = f2bf(tl[tx][ty + i * 8]);
    }
}

// ---------------- QKV GEMM: 128x128x32 2-phase double-buffered, gl_lds staging ----------------
// Q,K row-major bf16; V stored TRANSPOSED [b][h][d][s] (via LDS-transpose epilogue)
__global__ __launch_bounds__(256) void qkv_gemm(const unsigned short* __restrict__ xb,
        const unsigned short* __restrict__ wt,
        const float* __restrict__ biasq, const float* __restrict__ biask,
        const float* __restrict__ biasv,
        unsigned short* __restrict__ qk, unsigned short* __restrict__ vtg) {
    __shared__ unsigned short lds[16384];      // A bufs @0,4096; B bufs @8192,12288; reused for V transpose
    unsigned short* ldsA = lds;
    unsigned short* ldsB = lds + 8192;

    // mtile-major XCD mapping: XCD x owns mtiles [x*8, x*8+8) x all 18 ntiles
    // -> A-panel (1.57MB) + B-panel (196KB) stay L2-resident; A fetched from HBM once
    int bid = blockIdx.x;
    int mtile = (bid & 7) * 8 + ((bid >> 3) & 7);
    int ntile = bid >> 6;                      // 0..17
    int m0 = mtile * 128;
    int wsel = ntile / 6;
    int nb0 = ntile * 128 - wsel * E_;         // col offset within this weight
    const float* bias = wsel == 0 ? biasq : (wsel == 1 ? biask : biasv);
    float scale = wsel == 0 ? 0.125f : 1.0f;

    int t = threadIdx.x, lane = t & 63, w = t >> 6;
    int l15 = lane & 15, l4 = lane >> 4;
    int wm = w >> 1, wn = w & 1;

    // staging decode: lane covers row rs (within 64-half), slot = lane&3;
    // global chunk = slot ^ ((row>>1)&3)
    int rs = w * 16 + (lane >> 2);
    int cg = ((lane & 3) ^ ((rs >> 1) & 3)) * 8;
    const unsigned short* agp = xb + (size_t)(m0 + rs) * E_ + cg;
    const unsigned short* bgp = wt + (size_t)(wsel * E_ + nb0 + rs) * E_ + cg;

    f32x4 acc[4][4];
    #pragma unroll
    for (int f = 0; f < 4; f++)
        #pragma unroll
        for (int g = 0; g < 4; g++)
            acc[f][g] = (f32x4){0.f, 0.f, 0.f, 0.f};

    auto stage = [&](int kk, int buf) {
        gl_lds16(agp + kk,             ldsA + buf * 4096 + w * 512);
        gl_lds16(agp + kk + 64 * E_,   ldsA + buf * 4096 + 2048 + w * 512);
        gl_lds16(bgp + kk,             ldsB + buf * 4096 + w * 512);
        gl_lds16(bgp + kk + 64 * E_,   ldsB + buf * 4096 + 2048 + w * 512);
    };

    stage(0, 0);
    __syncthreads();

    int sA = (l4 ^ ((l15 >> 1) & 3)) * 8;      // swizzled k-slot for frag reads

    #pragma unroll 1
    for (int kt = 0; kt < 24; ++kt) {
        int buf = kt & 1;
        if (kt < 23) stage((kt + 1) * 32, buf ^ 1);
        bf16x8 a[4], b[4];
        #pragma unroll
        for (int f = 0; f < 4; f++)
            a[f] = *(const bf16x8*)&ldsA[buf * 4096 + (wm * 64 + f * 16 + l15) * 32 + sA];
        #pragma unroll
        for (int g = 0; g < 4; g++)
            b[g] = *(const bf16x8*)&ldsB[buf * 4096 + (wn * 64 + g * 16 + l15) * 32 + sA];
        #pragma unroll
        for (int f = 0; f < 4; f++)
            #pragma unroll
            for (int g = 0; g < 4; g++)
                acc[f][g] = __builtin_amdgcn_mfma_f32_16x16x32_bf16(a[f], b[g], acc[f][g], 0, 0, 0);
        __syncthreads();   // drains vmcnt (stage done) + all reads of buf done
    }

    if (wsel < 2) {
        // Q/K epilogue: row-major stores
        #pragma unroll
        for (int f = 0; f < 4; f++) {
            int row0 = m0 + wm * 64 + f * 16 + l4 * 4;
            #pragma unroll
            for (int g = 0; g < 4; g++) {
                int col = nb0 + wn * 64 + g * 16 + l15;
                float bb = bias[col];
                #pragma unroll
                for (int r = 0; r < 4; r++) {
                    float v = (acc[f][g][r] + bb) * scale;
                    qk[(size_t)wsel * 8192 * E_ + (size_t)(row0 + r) * E_ + col] = f2bf(v);
                }
            }
        }
    } else {
        // V epilogue: transpose 128x128 tile in LDS (two 64-dcol passes), coalesced stores
        const int TST = 134;                   // padded stride (elems)
        int b2 = m0 >> 12;
        int s0 = m0 & 4095;
        #pragma unroll 1
        for (int p = 0; p < 2; ++p) {
            __syncthreads();                   // prior LDS use done
            #pragma unroll
            for (int gb = 0; gb < 2; ++gb) {
                int g = 2 * p + gb;
                int rid = wn * 32 + gb * 16 + l15;
                float bb = bias[nb0 + wn * 64 + g * 16 + l15];
                #pragma unroll
                for (int f = 0; f < 4; ++f) {
                    int sbase = wm * 64 + f * 16 + l4 * 4;
                    #pragma unroll
                    for (int r = 0; r < 4; ++r)
                        lds[rid * TST + sbase + r] = f2bf(acc[f][g][r] + bb);
                }
            }
            __syncthreads();
            int rid = t >> 2;
            int sc_ = (t & 3) * 32;
            int dcol = (rid >> 5) * 64 + (p * 2 + ((rid >> 4) & 1)) * 16 + (rid & 15);
            int gcol = nb0 + dcol;
            int hh = gcol >> 6, dd = gcol & 63;
            unsigned short* dst = vtg + ((size_t)(b2 * H_ + hh) * D_ + dd) * S_ + s0 + sc_;
            const unsigned short* srcl = lds + rid * TST + sc_;
            *(ushort8*)(dst)      = *(const ushort8*)(srcl);
            *(ushort8*)(dst + 8)  = *(const ushort8*)(srcl + 8);
            *(ushort8*)(dst + 16) = *(const ushort8*)(srcl + 16);
            *(ushort8*)(dst + 24) = *(const ushort8*)(srcl + 24);
        }
    }
}

// ---------------- banded flash attention: LDS-staged K + V^T, swapped QK^T, O^T PV ----------------
__global__ __launch_bounds__(256) void attn(const unsigned short* __restrict__ qk,
        const unsigned short* __restrict__ vtg,
        const float* __restrict__ amask, float* __restrict__ out) {
    __shared__ unsigned short klds[2][2048];   // [buf] 32 rows x 64 cols, chunk-swizzled
    __shared__ unsigned short vlds[2][2048];   // [buf] V^T: 64 d-rows x 32 keys, linear
    __shared__ unsigned short plds[4][16 * 40];// per-wave P [16 q][32 keys], pad to 40

    // XCD-pinning: all 64 q-tiles of one (b,h) on one XCD
    int bid = blockIdx.x;
    int xcd = bid & 7;
    int j = bid >> 3;
    int qt = j & 63;
    int p_ = xcd + 8 * (j >> 6);
    int h = p_ % H_;
    int b = p_ / H_;

    int t = threadIdx.x, lane = t & 63, wv = t >> 6;
    int l15 = lane & 15, l4 = lane >> 4;
    const unsigned short* qp = qk;
    const unsigned short* kp = qk + (size_t)8192 * E_;
    size_t rowbase = (size_t)b * S_;
    int hcol = h * D_;
    const unsigned short* vth = vtg + (size_t)(b * H_ + h) * D_ * S_;
    const float* amb = amask + (size_t)b * S_;

    int q0 = qt * 64 + wv * 16;
    int myq = q0 + l15;
    bf16x8 qf[2];
    {
        const unsigned short* qrow = qp + (rowbase + myq) * E_ + hcol;
        qf[0] = *(const bf16x8*)(qrow + l4 * 8);
        qf[1] = *(const bf16x8*)(qrow + 32 + l4 * 8);
    }

    int kt0 = qt * 64 - 256;
    bool interior = (qt >= 4) && (qt <= 59);

    // staging thread-constant decode
    int rK = t >> 3;                                   // K row 0..31
    int cK = (((t & 7) ^ (rK & 7)) << 3);              // swizzled chunk -> elem off
    const unsigned short* kbase_g = kp + rowbase * E_ + hcol + cK;
    int dV = t >> 2;                                   // V^T d-row 0..63
    int kcV = (t & 3) << 3;                            // key chunk 0,8,16,24
    const unsigned short* vbase_g = vth + (size_t)dV * S_;

    auto stage = [&](int bt, int buf) {
        int kg = kt0 + bt * 32;
        int kk = min(max(kg + rK, 0), S_ - 1);
        gl_lds16(kbase_g + (size_t)kk * E_, &klds[buf][wv * 512]);
        int vb = min(max(kg + kcV, 0), S_ - 8);        // kg multiple of 32 -> chunk all-in or all-out
        gl_lds16(vbase_g + vb, &vlds[buf][wv * 512]);
    };

    float mrun = -1e8f, lpart = 0.f;
    f32x4 oaccT[4];
    #pragma unroll
    for (int d4 = 0; d4 < 4; d4++) oaccT[d4] = (f32x4){0.f, 0.f, 0.f, 0.f};
    unsigned short* pl = (unsigned short*)plds[wv];

    stage(0, 0);

    #pragma unroll 1
    for (int bt = 0; bt < 18; ++bt) {
        int buf = bt & 1;
        __syncthreads();                       // stage(bt) landed; buf^1 free
        if (bt + 1 < 18) stage(bt + 1, buf ^ 1);
        int kg = kt0 + bt * 32;

        // --- additive mask (key-only); issue loads early
        float fm[8];
        #pragma unroll
        for (int nt = 0; nt < 2; nt++) {
            int idx = kg + nt * 16 + l4 * 4;
            float4 a4 = make_float4(0.f, 0.f, 0.f, 0.f);
            if (idx >= 0 && idx <= S_ - 4) a4 = *(const float4*)(amb + idx);
            fm[nt * 4 + 0] = (a4.x != 0.f) ? -10000.f : 0.f;
            fm[nt * 4 + 1] = (a4.y != 0.f) ? -10000.f : 0.f;
            fm[nt * 4 + 2] = (a4.z != 0.f) ? -10000.f : 0.f;
            fm[nt * 4 + 3] = (a4.w != 0.f) ? -10000.f : 0.f;
        }

        // --- K A-frags from swizzled LDS
        const unsigned short* kb = &klds[buf][l15 * 64];
        int c0 = ((l4 ^ (l15 & 7)) << 3);
        int c1 = (((4 + l4) ^ (l15 & 7)) << 3);
        bf16x8 kf00 = *(const bf16x8*)(kb + c0);
        bf16x8 kf01 = *(const bf16x8*)(kb + c1);
        bf16x8 kf10 = *(const bf16x8*)(kb + 1024 + c0);
        bf16x8 kf11 = *(const bf16x8*)(kb + 1024 + c1);

        // --- V^T A-frags (plain b128): vf[d4] = V^T[d4*16+l15][keys l4*8..+7]
        bf16x8 vf[4];
        #pragma unroll
        for (int d4 = 0; d4 < 4; d4++)
            vf[d4] = *(const bf16x8*)(&vlds[buf][(d4 * 16 + l15) * 32 + l4 * 8]);

        // --- swapped QK^T: st[nt][r] = S^T[key=kg+nt*16+l4*4+r][q=myq]
        f32x4 z = (f32x4){0.f, 0.f, 0.f, 0.f};
        f32x4 st0 = __builtin_amdgcn_mfma_f32_16x16x32_bf16(kf00, qf[0], z, 0, 0, 0);
        st0 = __builtin_amdgcn_mfma_f32_16x16x32_bf16(kf01, qf[1], st0, 0, 0, 0);
        f32x4 st1 = __builtin_amdgcn_mfma_f32_16x16x32_bf16(kf10, qf[0], z, 0, 0, 0);
        st1 = __builtin_amdgcn_mfma_f32_16x16x32_bf16(kf11, qf[1], st1, 0, 0, 0);

        bool full = interior && (bt >= 1 + (wv >> 1)) && (bt <= 15 + (wv >> 1));
        float sv[8];
        if (full) {
            #pragma unroll
            for (int r = 0; r < 4; r++) { sv[r] = st0[r] + fm[r]; sv[4 + r] = st1[r] + fm[4 + r]; }
        } else {
            #pragma unroll
            for (int i = 0; i < 8; i++) {
                int key = kg + (i >> 2) * 16 + l4 * 4 + (i & 3);
                int dd = key - myq;
                bool valid = (key >= 0) && (key < S_) && (dd <= 256) && (dd >= -256);
                float s = (i < 4) ? st0[i & 3] : st1[i & 3];
                sv[i] = valid ? (s + fm[i]) : -1e30f;
            }
        }

        // --- defer-max online softmax
        float mt = sv[0];
        #pragma unroll
        for (int i = 1; i < 8; i++) mt = fmaxf(mt, sv[i]);
        if (__any(mt - mrun > 8.f)) {
            float mw = fmaxf(mt, __shfl_xor(mt, 16));
            mw = fmaxf(mw, __shfl_xor(mw, 32));
            float mnew = fmaxf(mrun, mw);
            float sc = __expf(mrun - mnew);   // uniform over l4 for fixed l15=q
            mrun = mnew;
            lpart *= sc;
            #pragma unroll
            for (int d4 = 0; d4 < 4; d4++) {
                oaccT[d4][0] *= sc; oaccT[d4][1] *= sc; oaccT[d4][2] *= sc; oaccT[d4][3] *= sc;
            }
        }
        bf16x4 pb0, pb1;
        float ps = 0.f;
        #pragma unroll
        for (int r = 0; r < 4; r++) {
            float e0 = __expf(sv[r] - mrun);
            float e1 = __expf(sv[4 + r] - mrun);
            ps += e0 + e1;
            pb0[r] = (__bf16)e0;
            pb1[r] = (__bf16)e1;
        }
        lpart += ps;

        // --- P round-trip through per-wave LDS: P[q=l15][key]
        *(ushort4v*)(pl + l15 * 40 + l4 * 4)      = __builtin_bit_cast(ushort4v, pb0);
        *(ushort4v*)(pl + l15 * 40 + 16 + l4 * 4) = __builtin_bit_cast(ushort4v, pb1);
        asm volatile("s_waitcnt lgkmcnt(0)" ::: "memory");
        __builtin_amdgcn_sched_barrier(0);
        bf16x8 pf = *(const bf16x8*)(pl + l15 * 40 + l4 * 8);   // P^T B-frag

        // --- PV: O^T[d][q] += V^T x P^T
        #pragma unroll
        for (int d4 = 0; d4 < 4; d4++)
            oaccT[d4] = __builtin_amdgcn_mfma_f32_16x16x32_bf16(vf[d4], pf, oaccT[d4], 0, 0, 0);
    }

    // --- epilogue (all lane-local: q = l15)
    float lsum = lpart + __shfl_xor(lpart, 16);
    lsum += __shfl_xor(lsum, 32);
    float inv = 1.0f / lsum;
    if (amb[q0 + l15] < 0.f) inv = 0.f;
    float* orow = out + (rowbase + q0 + l15) * E_ + hcol;
    #pragma unroll
    for (int d4 = 0; d4 < 4; d4++) {
        float4 o4;
        o4.x = oaccT[d4][0] * inv;
        o4.y = oaccT[d4][1] * inv;
        o4.z = oaccT[d4][2] * inv;
        o4.w = oaccT[d4][3] * inv;
        *(float4*)(orow + d4 * 16 + l4 * 4) = o4;
    }
}

extern "C" void kernel_launch(void* const* d_in, const int* in_sizes, int n_in,
                              void* d_out, int out_size, void* d_ws, size_t ws_size,
                              hipStream_t stream) {
    const float* hs = (const float*)d_in[0];
    const float* am = (const float*)d_in[1];
    const float* Wq = (const float*)d_in[2];
    const float* bq = (const float*)d_in[3];
    const float* Wk = (const float*)d_in[4];
    const float* bk = (const float*)d_in[5];
    const float* Wv = (const float*)d_in[6];
    const float* bv = (const float*)d_in[7];
    float* out = (float*)d_out;
    unsigned short* xb  = (unsigned short*)d_ws;                  // 8192*768
    unsigned short* wtp = xb + (size_t)8192 * E_;                 // 3*768*768
    unsigned short* qkb = wtp + (size_t)3 * E_ * E_;              // 2*8192*768 (Q,K)
    unsigned short* vtg = qkb + (size_t)2 * 8192 * E_;            // 2*12*64*4096 (V^T)

    hipLaunchKernelGGL(cvt_x, dim3(2048), dim3(256), 0, stream, hs, xb, 8192 * E_ / 4);
    hipLaunchKernelGGL(cvt_w, dim3(24, 24, 3), dim3(32, 8), 0, stream, Wq, Wk, Wv, wtp);
    hipLaunchKernelGGL(qkv_gemm, dim3(1152), dim3(256), 0, stream, xb, wtp, bq, bk, bv, qkb, vtg);
    hipLaunchKernelGGL(attn, dim3(1536), dim3(256), 0, stream, qkb, vtg, am, out);
}

// Round 8
// 113.222 us; speedup vs baseline: 3.0106x; 3.0106x over previous
//
#include <hip/hip_runtime.h>
#include <hip/hip_bf16.h>
#include <cstdint>

#define B_ 2
#define S_ 4096
#define E_ 768
#define H_ 12
#define D_ 64

typedef __bf16 bf16x8 __attribute__((ext_vector_type(8)));
typedef __bf16 bf16x4 __attribute__((ext_vector_type(4)));
typedef float f32x4 __attribute__((ext_vector_type(4)));
typedef unsigned short ushort8 __attribute__((ext_vector_type(8)));
typedef unsigned short ushort4v __attribute__((ext_vector_type(4)));

static __device__ __forceinline__ unsigned short f2bf(float f) {
    union { float f; uint32_t u; } v; v.f = f;
    uint32_t u = v.u;
    u += 0x7FFFu + ((u >> 16) & 1u);
    return (unsigned short)(u >> 16);
}

static __device__ __forceinline__ void gl_lds16(const unsigned short* g, unsigned short* l) {
    __builtin_amdgcn_global_load_lds((const __attribute__((address_space(1))) unsigned int*)g,
                                     (__attribute__((address_space(3))) unsigned int*)l, 16, 0, 0);
}

// ---------------- convert hidden_states fp32 -> bf16 ----------------
__global__ void cvt_x(const float* __restrict__ x, unsigned short* __restrict__ xb, int n4) {
    int i = blockIdx.x * blockDim.x + threadIdx.x;
    int stride = gridDim.x * blockDim.x;
    for (; i < n4; i += stride) {
        float4 f = ((const float4*)x)[i];
        ushort4v o;
        o.x = f2bf(f.x); o.y = f2bf(f.y); o.z = f2bf(f.z); o.w = f2bf(f.w);
        ((ushort4v*)xb)[i] = o;
    }
}

// ---------------- convert + transpose weights: WT[n][k] = W[k][n], bf16 ----------------
__global__ void cvt_w(const float* __restrict__ Wq, const float* __restrict__ Wk,
                      const float* __restrict__ Wv, unsigned short* __restrict__ wt) {
    __shared__ float tl[32][33];
    int wsel = blockIdx.z;
    const float* src = wsel == 0 ? Wq : (wsel == 1 ? Wk : Wv);
    int tx = threadIdx.x, ty = threadIdx.y;
    int n0 = blockIdx.x * 32, k0 = blockIdx.y * 32;
    for (int i = 0; i < 4; i++) {
        int k = k0 + ty + i * 8;
        tl[ty + i * 8][tx] = src[(size_t)k * E_ + n0 + tx];
    }
    __syncthreads();
    unsigned short* dst = wt + (size_t)wsel * E_ * E_;
    for (int i = 0; i < 4; i++) {
        int n = n0 + ty + i * 8;
        dst[(size_t)n * E_ + k0 + tx] = f2bf(tl[tx][ty + i * 8]);
    }
}

// ---------------- QKV GEMM: 128x128x32 2-phase double-buffered, gl_lds staging ----------------
// Q,K row-major bf16; V stored TRANSPOSED [b][h][d][s] (via LDS-transpose epilogue)
__global__ __launch_bounds__(256) void qkv_gemm(const unsigned short* __restrict__ xb,
        const unsigned short* __restrict__ wt,
        const float* __restrict__ biasq, const float* __restrict__ biask,
        const float* __restrict__ biasv,
        unsigned short* __restrict__ qk, unsigned short* __restrict__ vtg) {
    __shared__ unsigned short lds[16384];      // A bufs @0,4096; B bufs @8192,12288; reused for V transpose
    unsigned short* ldsA = lds;
    unsigned short* ldsB = lds + 8192;

    // mtile-major XCD mapping: XCD x owns mtiles [x*8, x*8+8) x all 18 ntiles
    int bid = blockIdx.x;
    int mtile = (bid & 7) * 8 + ((bid >> 3) & 7);
    int ntile = bid >> 6;                      // 0..17
    int m0 = mtile * 128;
    int wsel = ntile / 6;
    int nb0 = ntile * 128 - wsel * E_;         // col offset within this weight
    const float* bias = wsel == 0 ? biasq : (wsel == 1 ? biask : biasv);
    float scale = wsel == 0 ? 0.125f : 1.0f;

    int t = threadIdx.x, lane = t & 63, w = t >> 6;
    int l15 = lane & 15, l4 = lane >> 4;
    int wm = w >> 1, wn = w & 1;

    // staging decode: lane covers row rs (within 64-half), slot = lane&3;
    // global chunk = slot ^ ((row>>1)&3)
    int rs = w * 16 + (lane >> 2);
    int cg = ((lane & 3) ^ ((rs >> 1) & 3)) * 8;
    const unsigned short* agp = xb + (size_t)(m0 + rs) * E_ + cg;
    const unsigned short* bgp = wt + (size_t)(wsel * E_ + nb0 + rs) * E_ + cg;

    f32x4 acc[4][4];
    #pragma unroll
    for (int f = 0; f < 4; f++)
        #pragma unroll
        for (int g = 0; g < 4; g++)
            acc[f][g] = (f32x4){0.f, 0.f, 0.f, 0.f};

    auto stage = [&](int kk, int buf) {
        gl_lds16(agp + kk,             ldsA + buf * 4096 + w * 512);
        gl_lds16(agp + kk + 64 * E_,   ldsA + buf * 4096 + 2048 + w * 512);
        gl_lds16(bgp + kk,             ldsB + buf * 4096 + w * 512);
        gl_lds16(bgp + kk + 64 * E_,   ldsB + buf * 4096 + 2048 + w * 512);
    };

    stage(0, 0);
    __syncthreads();

    int sA = (l4 ^ ((l15 >> 1) & 3)) * 8;      // swizzled k-slot for frag reads

    #pragma unroll 1
    for (int kt = 0; kt < 24; ++kt) {
        int buf = kt & 1;
        if (kt < 23) stage((kt + 1) * 32, buf ^ 1);
        bf16x8 a[4], b[4];
        #pragma unroll
        for (int f = 0; f < 4; f++)
            a[f] = *(const bf16x8*)&ldsA[buf * 4096 + (wm * 64 + f * 16 + l15) * 32 + sA];
        #pragma unroll
        for (int g = 0; g < 4; g++)
            b[g] = *(const bf16x8*)&ldsB[buf * 4096 + (wn * 64 + g * 16 + l15) * 32 + sA];
        #pragma unroll
        for (int f = 0; f < 4; f++)
            #pragma unroll
            for (int g = 0; g < 4; g++)
                acc[f][g] = __builtin_amdgcn_mfma_f32_16x16x32_bf16(a[f], b[g], acc[f][g], 0, 0, 0);
        __syncthreads();   // drains vmcnt (stage done) + all reads of buf done
    }

    if (wsel < 2) {
        // Q/K epilogue: row-major stores
        #pragma unroll
        for (int f = 0; f < 4; f++) {
            int row0 = m0 + wm * 64 + f * 16 + l4 * 4;
            #pragma unroll
            for (int g = 0; g < 4; g++) {
                int col = nb0 + wn * 64 + g * 16 + l15;
                float bb = bias[col];
                #pragma unroll
                for (int r = 0; r < 4; r++) {
                    float v = (acc[f][g][r] + bb) * scale;
                    qk[(size_t)wsel * 8192 * E_ + (size_t)(row0 + r) * E_ + col] = f2bf(v);
                }
            }
        }
    } else {
        // V epilogue: transpose 128x128 tile in LDS (two 64-dcol passes), coalesced stores.
        // NOTE: p loop MUST be fully unrolled -> acc indices compile-time (rule #20:
        // runtime-indexed ext_vector arrays go to scratch; caused a 3.5x regression).
        const int TST = 134;                   // padded stride (elems)
        int b2 = m0 >> 12;
        int s0 = m0 & 4095;
        #pragma unroll
        for (int p = 0; p < 2; ++p) {
            __syncthreads();                   // prior LDS use done
            #pragma unroll
            for (int gb = 0; gb < 2; ++gb) {
                int g = 2 * p + gb;
                int rid = wn * 32 + gb * 16 + l15;
                float bb = bias[nb0 + wn * 64 + g * 16 + l15];
                #pragma unroll
                for (int f = 0; f < 4; ++f) {
                    int sbase = wm * 64 + f * 16 + l4 * 4;
                    #pragma unroll
                    for (int r = 0; r < 4; ++r)
                        lds[rid * TST + sbase + r] = f2bf(acc[f][g][r] + bb);
                }
            }
            __syncthreads();
            int rid = t >> 2;
            int sc_ = (t & 3) * 32;
            int dcol = (rid >> 5) * 64 + (p * 2 + ((rid >> 4) & 1)) * 16 + (rid & 15);
            int gcol = nb0 + dcol;
            int hh = gcol >> 6, dd = gcol & 63;
            unsigned short* dst = vtg + ((size_t)(b2 * H_ + hh) * D_ + dd) * S_ + s0 + sc_;
            const unsigned short* srcl = lds + rid * TST + sc_;
            *(ushort8*)(dst)      = *(const ushort8*)(srcl);
            *(ushort8*)(dst + 8)  = *(const ushort8*)(srcl + 8);
            *(ushort8*)(dst + 16) = *(const ushort8*)(srcl + 16);
            *(ushort8*)(dst + 24) = *(const ushort8*)(srcl + 24);
        }
    }
}

// ---------------- banded flash attention: LDS-staged K + V^T, swapped QK^T, O^T PV ----------------
__global__ __launch_bounds__(256) void attn(const unsigned short* __restrict__ qk,
        const unsigned short* __restrict__ vtg,
        const float* __restrict__ amask, float* __restrict__ out) {
    __shared__ unsigned short klds[2][2048];   // [buf] 32 rows x 64 cols, chunk-swizzled
    __shared__ unsigned short vlds[2][2048];   // [buf] V^T: 64 d-rows x 32 keys, linear
    __shared__ unsigned short plds[4][16 * 40];// per-wave P [16 q][32 keys], pad to 40

    // XCD-pinning: all 64 q-tiles of one (b,h) on one XCD
    int bid = blockIdx.x;
    int xcd = bid & 7;
    int j = bid >> 3;
    int qt = j & 63;
    int p_ = xcd + 8 * (j >> 6);
    int h = p_ % H_;
    int b = p_ / H_;

    int t = threadIdx.x, lane = t & 63, wv = t >> 6;
    int l15 = lane & 15, l4 = lane >> 4;
    const unsigned short* qp = qk;
    const unsigned short* kp = qk + (size_t)8192 * E_;
    size_t rowbase = (size_t)b * S_;
    int hcol = h * D_;
    const unsigned short* vth = vtg + (size_t)(b * H_ + h) * D_ * S_;
    const float* amb = amask + (size_t)b * S_;

    int q0 = qt * 64 + wv * 16;
    int myq = q0 + l15;
    bf16x8 qf[2];
    {
        const unsigned short* qrow = qp + (rowbase + myq) * E_ + hcol;
        qf[0] = *(const bf16x8*)(qrow + l4 * 8);
        qf[1] = *(const bf16x8*)(qrow + 32 + l4 * 8);
    }

    int kt0 = qt * 64 - 256;
    bool interior = (qt >= 4) && (qt <= 59);

    // staging thread-constant decode
    int rK = t >> 3;                                   // K row 0..31
    int cK = (((t & 7) ^ (rK & 7)) << 3);              // swizzled chunk -> elem off
    const unsigned short* kbase_g = kp + rowbase * E_ + hcol + cK;
    int dV = t >> 2;                                   // V^T d-row 0..63
    int kcV = (t & 3) << 3;                            // key chunk 0,8,16,24
    const unsigned short* vbase_g = vth + (size_t)dV * S_;

    auto stage = [&](int bt, int buf) {
        int kg = kt0 + bt * 32;
        int kk = min(max(kg + rK, 0), S_ - 1);
        gl_lds16(kbase_g + (size_t)kk * E_, &klds[buf][wv * 512]);
        int vb = min(max(kg + kcV, 0), S_ - 8);        // kg multiple of 32 -> chunk all-in or all-out
        gl_lds16(vbase_g + vb, &vlds[buf][wv * 512]);
    };

    float mrun = -1e8f, lpart = 0.f;
    f32x4 oaccT[4];
    #pragma unroll
    for (int d4 = 0; d4 < 4; d4++) oaccT[d4] = (f32x4){0.f, 0.f, 0.f, 0.f};
    unsigned short* pl = (unsigned short*)plds[wv];

    stage(0, 0);

    #pragma unroll 1
    for (int bt = 0; bt < 18; ++bt) {
        int buf = bt & 1;
        __syncthreads();                       // stage(bt) landed; buf^1 free
        if (bt + 1 < 18) stage(bt + 1, buf ^ 1);
        int kg = kt0 + bt * 32;

        // --- additive mask (key-only); issue loads early
        float fm[8];
        #pragma unroll
        for (int nt = 0; nt < 2; nt++) {
            int idx = kg + nt * 16 + l4 * 4;
            float4 a4 = make_float4(0.f, 0.f, 0.f, 0.f);
            if (idx >= 0 && idx <= S_ - 4) a4 = *(const float4*)(amb + idx);
            fm[nt * 4 + 0] = (a4.x != 0.f) ? -10000.f : 0.f;
            fm[nt * 4 + 1] = (a4.y != 0.f) ? -10000.f : 0.f;
            fm[nt * 4 + 2] = (a4.z != 0.f) ? -10000.f : 0.f;
            fm[nt * 4 + 3] = (a4.w != 0.f) ? -10000.f : 0.f;
        }

        // --- K A-frags from swizzled LDS
        const unsigned short* kb = &klds[buf][l15 * 64];
        int c0 = ((l4 ^ (l15 & 7)) << 3);
        int c1 = (((4 + l4) ^ (l15 & 7)) << 3);
        bf16x8 kf00 = *(const bf16x8*)(kb + c0);
        bf16x8 kf01 = *(const bf16x8*)(kb + c1);
        bf16x8 kf10 = *(const bf16x8*)(kb + 1024 + c0);
        bf16x8 kf11 = *(const bf16x8*)(kb + 1024 + c1);

        // --- V^T A-frags (plain b128): vf[d4] = V^T[d4*16+l15][keys l4*8..+7]
        bf16x8 vf[4];
        #pragma unroll
        for (int d4 = 0; d4 < 4; d4++)
            vf[d4] = *(const bf16x8*)(&vlds[buf][(d4 * 16 + l15) * 32 + l4 * 8]);

        // --- swapped QK^T: st[nt][r] = S^T[key=kg+nt*16+l4*4+r][q=myq]
        f32x4 z = (f32x4){0.f, 0.f, 0.f, 0.f};
        f32x4 st0 = __builtin_amdgcn_mfma_f32_16x16x32_bf16(kf00, qf[0], z, 0, 0, 0);
        st0 = __builtin_amdgcn_mfma_f32_16x16x32_bf16(kf01, qf[1], st0, 0, 0, 0);
        f32x4 st1 = __builtin_amdgcn_mfma_f32_16x16x32_bf16(kf10, qf[0], z, 0, 0, 0);
        st1 = __builtin_amdgcn_mfma_f32_16x16x32_bf16(kf11, qf[1], st1, 0, 0, 0);

        bool full = interior && (bt >= 1 + (wv >> 1)) && (bt <= 15 + (wv >> 1));
        float sv[8];
        if (full) {
            #pragma unroll
            for (int r = 0; r < 4; r++) { sv[r] = st0[r] + fm[r]; sv[4 + r] = st1[r] + fm[4 + r]; }
        } else {
            #pragma unroll
            for (int i = 0; i < 8; i++) {
                int key = kg + (i >> 2) * 16 + l4 * 4 + (i & 3);
                int dd = key - myq;
                bool valid = (key >= 0) && (key < S_) && (dd <= 256) && (dd >= -256);
                float s = (i < 4) ? st0[i & 3] : st1[i & 3];
                sv[i] = valid ? (s + fm[i]) : -1e30f;
            }
        }

        // --- defer-max online softmax
        float mt = sv[0];
        #pragma unroll
        for (int i = 1; i < 8; i++) mt = fmaxf(mt, sv[i]);
        if (__any(mt - mrun > 8.f)) {
            float mw = fmaxf(mt, __shfl_xor(mt, 16));
            mw = fmaxf(mw, __shfl_xor(mw, 32));
            float mnew = fmaxf(mrun, mw);
            float sc = __expf(mrun - mnew);   // uniform over l4 for fixed l15=q
            mrun = mnew;
            lpart *= sc;
            #pragma unroll
            for (int d4 = 0; d4 < 4; d4++) {
                oaccT[d4][0] *= sc; oaccT[d4][1] *= sc; oaccT[d4][2] *= sc; oaccT[d4][3] *= sc;
            }
        }
        bf16x4 pb0, pb1;
        float ps = 0.f;
        #pragma unroll
        for (int r = 0; r < 4; r++) {
            float e0 = __expf(sv[r] - mrun);
            float e1 = __expf(sv[4 + r] - mrun);
            ps += e0 + e1;
            pb0[r] = (__bf16)e0;
            pb1[r] = (__bf16)e1;
        }
        lpart += ps;

        // --- P round-trip through per-wave LDS: P[q=l15][key]
        *(ushort4v*)(pl + l15 * 40 + l4 * 4)      = __builtin_bit_cast(ushort4v, pb0);
        *(ushort4v*)(pl + l15 * 40 + 16 + l4 * 4) = __builtin_bit_cast(ushort4v, pb1);
        asm volatile("s_waitcnt lgkmcnt(0)" ::: "memory");
        __builtin_amdgcn_sched_barrier(0);
        bf16x8 pf = *(const bf16x8*)(pl + l15 * 40 + l4 * 8);   // P^T B-frag

        // --- PV: O^T[d][q] += V^T x P^T
        #pragma unroll
        for (int d4 = 0; d4 < 4; d4++)
            oaccT[d4] = __builtin_amdgcn_mfma_f32_16x16x32_bf16(vf[d4], pf, oaccT[d4], 0, 0, 0);
    }

    // --- epilogue (all lane-local: q = l15)
    float lsum = lpart + __shfl_xor(lpart, 16);
    lsum += __shfl_xor(lsum, 32);
    float inv = 1.0f / lsum;
    if (amb[q0 + l15] < 0.f) inv = 0.f;
    float* orow = out + (rowbase + q0 + l15) * E_ + hcol;
    #pragma unroll
    for (int d4 = 0; d4 < 4; d4++) {
        float4 o4;
        o4.x = oaccT[d4][0] * inv;
        o4.y = oaccT[d4][1] * inv;
        o4.z = oaccT[d4][2] * inv;
        o4.w = oaccT[d4][3] * inv;
        *(float4*)(orow + d4 * 16 + l4 * 4) = o4;
    }
}

extern "C" void kernel_launch(void* const* d_in, const int* in_sizes, int n_in,
                              void* d_out, int out_size, void* d_ws, size_t ws_size,
                              hipStream_t stream) {
    const float* hs = (const float*)d_in[0];
    const float* am = (const float*)d_in[1];
    const float* Wq = (const float*)d_in[2];
    const float* bq = (const float*)d_in[3];
    const float* Wk = (const float*)d_in[4];
    const float* bk = (const float*)d_in[5];
    const float* Wv = (const float*)d_in[6];
    const float* bv = (const float*)d_in[7];
    float* out = (float*)d_out;
    unsigned short* xb  = (unsigned short*)d_ws;                  // 8192*768
    unsigned short* wtp = xb + (size_t)8192 * E_;                 // 3*768*768
    unsigned short* qkb = wtp + (size_t)3 * E_ * E_;              // 2*8192*768 (Q,K)
    unsigned short* vtg = qkb + (size_t)2 * 8192 * E_;            // 2*12*64*4096 (V^T)

    hipLaunchKernelGGL(cvt_x, dim3(2048), dim3(256), 0, stream, hs, xb, 8192 * E_ / 4);
    hipLaunchKernelGGL(cvt_w, dim3(24, 24, 3), dim3(32, 8), 0, stream, Wq, Wk, Wv, wtp);
    hipLaunchKernelGGL(qkv_gemm, dim3(1152), dim3(256), 0, stream, xb, wtp, bq, bk, bv, qkb, vtg);
    hipLaunchKernelGGL(attn, dim3(1536), dim3(256), 0, stream, qkb, vtg, am, out);
}

// Round 9
// 109.888 us; speedup vs baseline: 3.1019x; 1.0303x over previous
//
#include <hip/hip_runtime.h>
#include <hip/hip_bf16.h>
#include <cstdint>

#define B_ 2
#define S_ 4096
#define E_ 768
#define H_ 12
#define D_ 64

typedef __bf16 bf16x8 __attribute__((ext_vector_type(8)));
typedef __bf16 bf16x4 __attribute__((ext_vector_type(4)));
typedef float f32x4 __attribute__((ext_vector_type(4)));
typedef unsigned short ushort8 __attribute__((ext_vector_type(8)));
typedef unsigned short ushort4v __attribute__((ext_vector_type(4)));

static __device__ __forceinline__ unsigned short f2bf(float f) {
    union { float f; uint32_t u; } v; v.f = f;
    uint32_t u = v.u;
    u += 0x7FFFu + ((u >> 16) & 1u);
    return (unsigned short)(u >> 16);
}

static __device__ __forceinline__ void gl_lds16(const unsigned short* g, unsigned short* l) {
    __builtin_amdgcn_global_load_lds((const __attribute__((address_space(1))) unsigned int*)g,
                                     (__attribute__((address_space(3))) unsigned int*)l, 16, 0, 0);
}

// ---------------- convert hidden_states fp32 -> bf16 ----------------
__global__ void cvt_x(const float* __restrict__ x, unsigned short* __restrict__ xb, int n4) {
    int i = blockIdx.x * blockDim.x + threadIdx.x;
    int stride = gridDim.x * blockDim.x;
    for (; i < n4; i += stride) {
        float4 f = ((const float4*)x)[i];
        ushort4v o;
        o.x = f2bf(f.x); o.y = f2bf(f.y); o.z = f2bf(f.z); o.w = f2bf(f.w);
        ((ushort4v*)xb)[i] = o;
    }
}

// ---------------- convert + transpose weights: WT[n][k] = W[k][n], bf16 ----------------
__global__ void cvt_w(const float* __restrict__ Wq, const float* __restrict__ Wk,
                      const float* __restrict__ Wv, unsigned short* __restrict__ wt) {
    __shared__ float tl[32][33];
    int wsel = blockIdx.z;
    const float* src = wsel == 0 ? Wq : (wsel == 1 ? Wk : Wv);
    int tx = threadIdx.x, ty = threadIdx.y;
    int n0 = blockIdx.x * 32, k0 = blockIdx.y * 32;
    for (int i = 0; i < 4; i++) {
        int k = k0 + ty + i * 8;
        tl[ty + i * 8][tx] = src[(size_t)k * E_ + n0 + tx];
    }
    __syncthreads();
    unsigned short* dst = wt + (size_t)wsel * E_ * E_;
    for (int i = 0; i < 4; i++) {
        int n = n0 + ty + i * 8;
        dst[(size_t)n * E_ + k0 + tx] = f2bf(tl[tx][ty + i * 8]);
    }
}

// ---------------- QKV GEMM: 128x128x32 2-phase double-buffered, gl_lds staging ----------------
// Q,K row-major bf16; V stored TRANSPOSED [b][h][d][s] (via LDS-transpose epilogue)
__global__ __launch_bounds__(256) void qkv_gemm(const unsigned short* __restrict__ xb,
        const unsigned short* __restrict__ wt,
        const float* __restrict__ biasq, const float* __restrict__ biask,
        const float* __restrict__ biasv,
        unsigned short* __restrict__ qk, unsigned short* __restrict__ vtg) {
    __shared__ unsigned short lds[16384];      // A bufs @0,4096; B bufs @8192,12288; reused for V transpose
    unsigned short* ldsA = lds;
    unsigned short* ldsB = lds + 8192;

    // mtile-major XCD mapping: XCD x owns mtiles [x*8, x*8+8) x all 18 ntiles
    int bid = blockIdx.x;
    int mtile = (bid & 7) * 8 + ((bid >> 3) & 7);
    int ntile = bid >> 6;                      // 0..17
    int m0 = mtile * 128;
    int wsel = ntile / 6;
    int nb0 = ntile * 128 - wsel * E_;         // col offset within this weight
    const float* bias = wsel == 0 ? biasq : (wsel == 1 ? biask : biasv);
    float scale = wsel == 0 ? 0.125f : 1.0f;

    int t = threadIdx.x, lane = t & 63, w = t >> 6;
    int l15 = lane & 15, l4 = lane >> 4;
    int wm = w >> 1, wn = w & 1;

    // staging decode: lane covers row rs (within 64-half), slot = lane&3;
    // global chunk = slot ^ ((row>>1)&3)
    int rs = w * 16 + (lane >> 2);
    int cg = ((lane & 3) ^ ((rs >> 1) & 3)) * 8;
    const unsigned short* agp = xb + (size_t)(m0 + rs) * E_ + cg;
    const unsigned short* bgp = wt + (size_t)(wsel * E_ + nb0 + rs) * E_ + cg;

    f32x4 acc[4][4];
    #pragma unroll
    for (int f = 0; f < 4; f++)
        #pragma unroll
        for (int g = 0; g < 4; g++)
            acc[f][g] = (f32x4){0.f, 0.f, 0.f, 0.f};

    auto stage = [&](int kk, int buf) {
        gl_lds16(agp + kk,             ldsA + buf * 4096 + w * 512);
        gl_lds16(agp + kk + 64 * E_,   ldsA + buf * 4096 + 2048 + w * 512);
        gl_lds16(bgp + kk,             ldsB + buf * 4096 + w * 512);
        gl_lds16(bgp + kk + 64 * E_,   ldsB + buf * 4096 + 2048 + w * 512);
    };

    stage(0, 0);
    __syncthreads();

    int sA = (l4 ^ ((l15 >> 1) & 3)) * 8;      // swizzled k-slot for frag reads

    #pragma unroll 1
    for (int kt = 0; kt < 24; ++kt) {
        int buf = kt & 1;
        if (kt < 23) stage((kt + 1) * 32, buf ^ 1);
        bf16x8 a[4], b[4];
        #pragma unroll
        for (int f = 0; f < 4; f++)
            a[f] = *(const bf16x8*)&ldsA[buf * 4096 + (wm * 64 + f * 16 + l15) * 32 + sA];
        #pragma unroll
        for (int g = 0; g < 4; g++)
            b[g] = *(const bf16x8*)&ldsB[buf * 4096 + (wn * 64 + g * 16 + l15) * 32 + sA];
        #pragma unroll
        for (int f = 0; f < 4; f++)
            #pragma unroll
            for (int g = 0; g < 4; g++)
                acc[f][g] = __builtin_amdgcn_mfma_f32_16x16x32_bf16(a[f], b[g], acc[f][g], 0, 0, 0);
        __syncthreads();   // drains vmcnt (stage done) + all reads of buf done
    }

    if (wsel < 2) {
        // Q/K epilogue: row-major stores
        #pragma unroll
        for (int f = 0; f < 4; f++) {
            int row0 = m0 + wm * 64 + f * 16 + l4 * 4;
            #pragma unroll
            for (int g = 0; g < 4; g++) {
                int col = nb0 + wn * 64 + g * 16 + l15;
                float bb = bias[col];
                #pragma unroll
                for (int r = 0; r < 4; r++) {
                    float v = (acc[f][g][r] + bb) * scale;
                    qk[(size_t)wsel * 8192 * E_ + (size_t)(row0 + r) * E_ + col] = f2bf(v);
                }
            }
        }
    } else {
        // V epilogue: transpose 128x128 tile in LDS (two 64-dcol passes), coalesced stores.
        // p loop fully unrolled -> acc indices compile-time (rule #20).
        const int TST = 134;                   // padded stride (elems)
        int b2 = m0 >> 12;
        int s0 = m0 & 4095;
        #pragma unroll
        for (int p = 0; p < 2; ++p) {
            __syncthreads();                   // prior LDS use done
            #pragma unroll
            for (int gb = 0; gb < 2; ++gb) {
                int g = 2 * p + gb;
                int rid = wn * 32 + gb * 16 + l15;
                float bb = bias[nb0 + wn * 64 + g * 16 + l15];
                #pragma unroll
                for (int f = 0; f < 4; ++f) {
                    int sbase = wm * 64 + f * 16 + l4 * 4;
                    #pragma unroll
                    for (int r = 0; r < 4; ++r)
                        lds[rid * TST + sbase + r] = f2bf(acc[f][g][r] + bb);
                }
            }
            __syncthreads();
            int rid = t >> 2;
            int sc_ = (t & 3) * 32;
            int dcol = (rid >> 5) * 64 + (p * 2 + ((rid >> 4) & 1)) * 16 + (rid & 15);
            int gcol = nb0 + dcol;
            int hh = gcol >> 6, dd = gcol & 63;
            unsigned short* dst = vtg + ((size_t)(b2 * H_ + hh) * D_ + dd) * S_ + s0 + sc_;
            const unsigned short* srcl = lds + rid * TST + sc_;
            *(ushort8*)(dst)      = *(const ushort8*)(srcl);
            *(ushort8*)(dst + 8)  = *(const ushort8*)(srcl + 8);
            *(ushort8*)(dst + 16) = *(const ushort8*)(srcl + 16);
            *(ushort8*)(dst + 24) = *(const ushort8*)(srcl + 24);
        }
    }
}

// ---------------- banded flash attention: LDS-staged K + V^T, swapped QK^T, O^T PV ----------------
__global__ __launch_bounds__(256) void attn(const unsigned short* __restrict__ qk,
        const unsigned short* __restrict__ vtg,
        const float* __restrict__ amask, float* __restrict__ out) {
    __shared__ unsigned short klds[2][2048];   // [buf] 32 rows x 64 cols, chunk-swizzled
    __shared__ unsigned short vlds[2][2048];   // [buf] V^T: 64 d-rows x 32 keys, chunk-swizzled
    __shared__ unsigned short plds[4][16 * 40];// per-wave P [16 q][32 keys], pad to 40
    __shared__ float fmlds[576];               // per-key additive mask, block-constant

    // XCD-pinning: all 64 q-tiles of one (b,h) on one XCD
    int bid = blockIdx.x;
    int xcd = bid & 7;
    int j = bid >> 3;
    int qt = j & 63;
    int p_ = xcd + 8 * (j >> 6);
    int h = p_ % H_;
    int b = p_ / H_;

    int t = threadIdx.x, lane = t & 63, wv = t >> 6;
    int l15 = lane & 15, l4 = lane >> 4;
    const unsigned short* qp = qk;
    const unsigned short* kp = qk + (size_t)8192 * E_;
    size_t rowbase = (size_t)b * S_;
    int hcol = h * D_;
    const unsigned short* vth = vtg + (size_t)(b * H_ + h) * D_ * S_;
    const float* amb = amask + (size_t)b * S_;

    int q0 = qt * 64 + wv * 16;
    int myq = q0 + l15;
    bf16x8 qf[2];
    {
        const unsigned short* qrow = qp + (rowbase + myq) * E_ + hcol;
        qf[0] = *(const bf16x8*)(qrow + l4 * 8);
        qf[1] = *(const bf16x8*)(qrow + 32 + l4 * 8);
    }

    int kt0 = qt * 64 - 256;
    bool interior = (qt >= 4) && (qt <= 59);

    // --- per-key additive mask, computed once (key-only, amortized over 18 iters)
    for (int i = t; i < 576; i += 256) {
        int key = kt0 + i;
        float v = 0.f;
        if (key >= 0 && key < S_) v = (amb[key] != 0.f) ? -10000.f : 0.f;
        fmlds[i] = v;
    }

    // staging thread-constant decode
    int rK = t >> 3;                                   // K row 0..31
    int cK = (((t & 7) ^ (rK & 7)) << 3);              // swizzled chunk -> elem off
    const unsigned short* kbase_g = kp + rowbase * E_ + hcol + cK;
    int dV = t >> 2;                                   // V^T d-row 0..63
    int kcV = ((t & 3) ^ ((dV >> 1) & 3)) << 3;        // swizzled key chunk (2-way banks on read)
    const unsigned short* vbase_g = vth + (size_t)dV * S_;

    auto stage = [&](int bt, int buf) {
        int kg = kt0 + bt * 32;
        int kk = min(max(kg + rK, 0), S_ - 1);
        gl_lds16(kbase_g + (size_t)kk * E_, &klds[buf][wv * 512]);
        int vb = min(max(kg + kcV, 0), S_ - 8);        // kg multiple of 32 -> chunk all-in or all-out
        gl_lds16(vbase_g + vb, &vlds[buf][wv * 512]);
    };

    float mrun = -1e8f, lpart = 0.f;
    f32x4 oaccT[4];
    #pragma unroll
    for (int d4 = 0; d4 < 4; d4++) oaccT[d4] = (f32x4){0.f, 0.f, 0.f, 0.f};
    unsigned short* pl = (unsigned short*)plds[wv];

    stage(0, 0);

    int sV = ((l4 ^ ((l15 >> 1) & 3)) << 3);           // V read slot

    #pragma unroll 1
    for (int bt = 0; bt < 18; ++bt) {
        int buf = bt & 1;
        __syncthreads();                       // stage(bt) + fm fill landed; buf^1 free
        if (bt + 1 < 18) stage(bt + 1, buf ^ 1);
        int kg = kt0 + bt * 32;

        // --- additive mask from LDS (broadcast reads, conflict-free)
        int fo = bt * 32 + l4 * 4;
        float4 a4 = *(const float4*)&fmlds[fo];
        float4 b4 = *(const float4*)&fmlds[fo + 16];
        float fm[8] = {a4.x, a4.y, a4.z, a4.w, b4.x, b4.y, b4.z, b4.w};

        // --- K A-frags from swizzled LDS
        const unsigned short* kb = &klds[buf][l15 * 64];
        int c0 = ((l4 ^ (l15 & 7)) << 3);
        int c1 = (((4 + l4) ^ (l15 & 7)) << 3);
        bf16x8 kf00 = *(const bf16x8*)(kb + c0);
        bf16x8 kf01 = *(const bf16x8*)(kb + c1);
        bf16x8 kf10 = *(const bf16x8*)(kb + 1024 + c0);
        bf16x8 kf11 = *(const bf16x8*)(kb + 1024 + c1);

        // --- V^T A-frags (swizzled slots): vf[d4] = V^T[d4*16+l15][keys l4*8..+7]
        bf16x8 vf[4];
        #pragma unroll
        for (int d4 = 0; d4 < 4; d4++)
            vf[d4] = *(const bf16x8*)(&vlds[buf][(d4 * 16 + l15) * 32 + sV]);

        // --- swapped QK^T: st[nt][r] = S^T[key=kg+nt*16+l4*4+r][q=myq]
        f32x4 z = (f32x4){0.f, 0.f, 0.f, 0.f};
        f32x4 st0 = __builtin_amdgcn_mfma_f32_16x16x32_bf16(kf00, qf[0], z, 0, 0, 0);
        st0 = __builtin_amdgcn_mfma_f32_16x16x32_bf16(kf01, qf[1], st0, 0, 0, 0);
        f32x4 st1 = __builtin_amdgcn_mfma_f32_16x16x32_bf16(kf10, qf[0], z, 0, 0, 0);
        st1 = __builtin_amdgcn_mfma_f32_16x16x32_bf16(kf11, qf[1], st1, 0, 0, 0);

        bool full = interior && (bt >= 1 + (wv >> 1)) && (bt <= 15 + (wv >> 1));
        float sv[8];
        if (full) {
            #pragma unroll
            for (int r = 0; r < 4; r++) { sv[r] = st0[r] + fm[r]; sv[4 + r] = st1[r] + fm[4 + r]; }
        } else {
            #pragma unroll
            for (int i = 0; i < 8; i++) {
                int key = kg + (i >> 2) * 16 + l4 * 4 + (i & 3);
                int dd = key - myq;
                bool valid = (key >= 0) && (key < S_) && (dd <= 256) && (dd >= -256);
                float s = (i < 4) ? st0[i & 3] : st1[i & 3];
                sv[i] = valid ? (s + fm[i]) : -1e30f;
            }
        }

        // --- defer-max online softmax
        float mt = fmaxf(fmaxf(fmaxf(sv[0], sv[1]), fmaxf(sv[2], sv[3])),
                         fmaxf(fmaxf(sv[4], sv[5]), fmaxf(sv[6], sv[7])));
        if (__any(mt - mrun > 8.f)) {
            float mw = fmaxf(mt, __shfl_xor(mt, 16));
            mw = fmaxf(mw, __shfl_xor(mw, 32));
            float mnew = fmaxf(mrun, mw);
            float sc = __expf(mrun - mnew);   // uniform over l4 for fixed l15=q
            mrun = mnew;
            lpart *= sc;
            #pragma unroll
            for (int d4 = 0; d4 < 4; d4++) {
                oaccT[d4][0] *= sc; oaccT[d4][1] *= sc; oaccT[d4][2] *= sc; oaccT[d4][3] *= sc;
            }
        }
        bf16x4 pb0, pb1;
        float ps = 0.f;
        #pragma unroll
        for (int r = 0; r < 4; r++) {
            float e0 = __expf(sv[r] - mrun);
            float e1 = __expf(sv[4 + r] - mrun);
            ps += e0 + e1;
            pb0[r] = (__bf16)e0;
            pb1[r] = (__bf16)e1;
        }
        lpart += ps;

        // --- P round-trip through per-wave LDS: P[q=l15][key]
        *(ushort4v*)(pl + l15 * 40 + l4 * 4)      = __builtin_bit_cast(ushort4v, pb0);
        *(ushort4v*)(pl + l15 * 40 + 16 + l4 * 4) = __builtin_bit_cast(ushort4v, pb1);
        asm volatile("s_waitcnt lgkmcnt(0)" ::: "memory");
        __builtin_amdgcn_sched_barrier(0);
        bf16x8 pf = *(const bf16x8*)(pl + l15 * 40 + l4 * 8);   // P^T B-frag

        // --- PV: O^T[d][q] += V^T x P^T
        #pragma unroll
        for (int d4 = 0; d4 < 4; d4++)
            oaccT[d4] = __builtin_amdgcn_mfma_f32_16x16x32_bf16(vf[d4], pf, oaccT[d4], 0, 0, 0);
    }

    // --- epilogue (all lane-local: q = l15)
    float lsum = lpart + __shfl_xor(lpart, 16);
    lsum += __shfl_xor(lsum, 32);
    float inv = 1.0f / lsum;
    if (amb[q0 + l15] < 0.f) inv = 0.f;
    float* orow = out + (rowbase + q0 + l15) * E_ + hcol;
    #pragma unroll
    for (int d4 = 0; d4 < 4; d4++) {
        float4 o4;
        o4.x = oaccT[d4][0] * inv;
        o4.y = oaccT[d4][1] * inv;
        o4.z = oaccT[d4][2] * inv;
        o4.w = oaccT[d4][3] * inv;
        *(float4*)(orow + d4 * 16 + l4 * 4) = o4;
    }
}

extern "C" void kernel_launch(void* const* d_in, const int* in_sizes, int n_in,
                              void* d_out, int out_size, void* d_ws, size_t ws_size,
                              hipStream_t stream) {
    const float* hs = (const float*)d_in[0];
    const float* am = (const float*)d_in[1];
    const float* Wq = (const float*)d_in[2];
    const float* bq = (const float*)d_in[3];
    const float* Wk = (const float*)d_in[4];
    const float* bk = (const float*)d_in[5];
    const float* Wv = (const float*)d_in[6];
    const float* bv = (const float*)d_in[7];
    float* out = (float*)d_out;
    unsigned short* xb  = (unsigned short*)d_ws;                  // 8192*768
    unsigned short* wtp = xb + (size_t)8192 * E_;                 // 3*768*768
    unsigned short* qkb = wtp + (size_t)3 * E_ * E_;              // 2*8192*768 (Q,K)
    unsigned short* vtg = qkb + (size_t)2 * 8192 * E_;            // 2*12*64*4096 (V^T)

    hipLaunchKernelGGL(cvt_x, dim3(2048), dim3(256), 0, stream, hs, xb, 8192 * E_ / 4);
    hipLaunchKernelGGL(cvt_w, dim3(24, 24, 3), dim3(32, 8), 0, stream, Wq, Wk, Wv, wtp);
    hipLaunchKernelGGL(qkv_gemm, dim3(1152), dim3(256), 0, stream, xb, wtp, bq, bk, bv, qkb, vtg);
    hipLaunchKernelGGL(attn, dim3(1536), dim3(256), 0, stream, qkb, vtg, am, out);
}

// Round 10
// 103.284 us; speedup vs baseline: 3.3003x; 1.0639x over previous
//
#include <hip/hip_runtime.h>
#include <hip/hip_bf16.h>
#include <cstdint>

#define B_ 2
#define S_ 4096
#define E_ 768
#define H_ 12
#define D_ 64
#define L2E 1.44269504088896f

typedef __bf16 bf16x8 __attribute__((ext_vector_type(8)));
typedef __bf16 bf16x4 __attribute__((ext_vector_type(4)));
typedef float f32x4 __attribute__((ext_vector_type(4)));
typedef unsigned short ushort8 __attribute__((ext_vector_type(8)));
typedef unsigned short ushort4v __attribute__((ext_vector_type(4)));

static __device__ __forceinline__ unsigned short f2bf(float f) {
    union { float f; uint32_t u; } v; v.f = f;
    uint32_t u = v.u;
    u += 0x7FFFu + ((u >> 16) & 1u);
    return (unsigned short)(u >> 16);
}

static __device__ __forceinline__ void gl_lds16(const unsigned short* g, unsigned short* l) {
    __builtin_amdgcn_global_load_lds((const __attribute__((address_space(1))) unsigned int*)g,
                                     (__attribute__((address_space(3))) unsigned int*)l, 16, 0, 0);
}

// ---------------- convert hidden_states fp32 -> bf16 ----------------
__global__ void cvt_x(const float* __restrict__ x, unsigned short* __restrict__ xb, int n4) {
    int i = blockIdx.x * blockDim.x + threadIdx.x;
    int stride = gridDim.x * blockDim.x;
    for (; i < n4; i += stride) {
        float4 f = ((const float4*)x)[i];
        ushort4v o;
        o.x = f2bf(f.x); o.y = f2bf(f.y); o.z = f2bf(f.z); o.w = f2bf(f.w);
        ((ushort4v*)xb)[i] = o;
    }
}

// ---------------- convert + transpose weights: WT[n][k] = W[k][n], bf16 ----------------
__global__ void cvt_w(const float* __restrict__ Wq, const float* __restrict__ Wk,
                      const float* __restrict__ Wv, unsigned short* __restrict__ wt) {
    __shared__ float tl[32][33];
    int wsel = blockIdx.z;
    const float* src = wsel == 0 ? Wq : (wsel == 1 ? Wk : Wv);
    int tx = threadIdx.x, ty = threadIdx.y;
    int n0 = blockIdx.x * 32, k0 = blockIdx.y * 32;
    for (int i = 0; i < 4; i++) {
        int k = k0 + ty + i * 8;
        tl[ty + i * 8][tx] = src[(size_t)k * E_ + n0 + tx];
    }
    __syncthreads();
    unsigned short* dst = wt + (size_t)wsel * E_ * E_;
    for (int i = 0; i < 4; i++) {
        int n = n0 + ty + i * 8;
        dst[(size_t)n * E_ + k0 + tx] = f2bf(tl[tx][ty + i * 8]);
    }
}

// ---------------- QKV GEMM: 128x128x32 2-phase double-buffered, gl_lds staging ----------------
// Q (pre-scaled by 0.125*log2e), K row-major bf16; V stored TRANSPOSED [b][h][d][s]
__global__ __launch_bounds__(256, 3) void qkv_gemm(const unsigned short* __restrict__ xb,
        const unsigned short* __restrict__ wt,
        const float* __restrict__ biasq, const float* __restrict__ biask,
        const float* __restrict__ biasv,
        unsigned short* __restrict__ qk, unsigned short* __restrict__ vtg) {
    __shared__ unsigned short lds[17920];      // A bufs @0,4096; B bufs @8192,12288; reused for epilogues
    unsigned short* ldsA = lds;
    unsigned short* ldsB = lds + 8192;

    // mtile-major XCD mapping: XCD x owns mtiles [x*8, x*8+8) x all 18 ntiles
    int bid = blockIdx.x;
    int mtile = (bid & 7) * 8 + ((bid >> 3) & 7);
    int ntile = bid >> 6;                      // 0..17
    int m0 = mtile * 128;
    int wsel = ntile / 6;
    int nb0 = ntile * 128 - wsel * E_;         // col offset within this weight
    const float* bias = wsel == 0 ? biasq : (wsel == 1 ? biask : biasv);
    float scale = wsel == 0 ? 0.125f * L2E : 1.0f;   // Q carries log2e for exp2 softmax

    int t = threadIdx.x, lane = t & 63, w = t >> 6;
    int l15 = lane & 15, l4 = lane >> 4;
    int wm = w >> 1, wn = w & 1;

    // staging decode: lane covers row rs (within 64-half), slot = lane&3;
    // global chunk = slot ^ ((row>>1)&3)
    int rs = w * 16 + (lane >> 2);
    int cg = ((lane & 3) ^ ((rs >> 1) & 3)) * 8;
    const unsigned short* agp = xb + (size_t)(m0 + rs) * E_ + cg;
    const unsigned short* bgp = wt + (size_t)(wsel * E_ + nb0 + rs) * E_ + cg;

    f32x4 acc[4][4];
    #pragma unroll
    for (int f = 0; f < 4; f++)
        #pragma unroll
        for (int g = 0; g < 4; g++)
            acc[f][g] = (f32x4){0.f, 0.f, 0.f, 0.f};

    auto stage = [&](int kk, int buf) {
        gl_lds16(agp + kk,             ldsA + buf * 4096 + w * 512);
        gl_lds16(agp + kk + 64 * E_,   ldsA + buf * 4096 + 2048 + w * 512);
        gl_lds16(bgp + kk,             ldsB + buf * 4096 + w * 512);
        gl_lds16(bgp + kk + 64 * E_,   ldsB + buf * 4096 + 2048 + w * 512);
    };

    stage(0, 0);
    __syncthreads();

    int sA = (l4 ^ ((l15 >> 1) & 3)) * 8;      // swizzled k-slot for frag reads

    #pragma unroll 1
    for (int kt = 0; kt < 24; ++kt) {
        int buf = kt & 1;
        if (kt < 23) stage((kt + 1) * 32, buf ^ 1);
        bf16x8 b[4];
        #pragma unroll
        for (int g = 0; g < 4; g++)
            b[g] = *(const bf16x8*)&ldsB[buf * 4096 + (wn * 64 + g * 16 + l15) * 32 + sA];
        #pragma unroll
        for (int f = 0; f < 4; f++) {
            bf16x8 af = *(const bf16x8*)&ldsA[buf * 4096 + (wm * 64 + f * 16 + l15) * 32 + sA];
            #pragma unroll
            for (int g = 0; g < 4; g++)
                acc[f][g] = __builtin_amdgcn_mfma_f32_16x16x32_bf16(af, b[g], acc[f][g], 0, 0, 0);
        }
        __syncthreads();   // drains vmcnt (stage done) + all reads of buf done
    }

    if (wsel < 2) {
        // Q/K epilogue: LDS transpose (stride 140 -> conflict-free writes), coalesced ushort8 stores
        const int QST = 140;
        #pragma unroll
        for (int f = 0; f < 4; f++) {
            #pragma unroll
            for (int g = 0; g < 4; g++) {
                int col = wn * 64 + g * 16 + l15;
                float bb = bias[nb0 + col];
                #pragma unroll
                for (int r = 0; r < 4; r++) {
                    int row = wm * 64 + f * 16 + l4 * 4 + r;
                    lds[row * QST + col] = f2bf((acc[f][g][r] + bb) * scale);
                }
            }
        }
        __syncthreads();
        int rr = t >> 4, l16 = t & 15;
        unsigned short* qbase = qk + (size_t)wsel * 8192 * E_;
        #pragma unroll
        for (int pas = 0; pas < 8; ++pas) {
            int row = pas * 16 + rr;
            ushort4v lo = *(const ushort4v*)&lds[row * QST + l16 * 8];
            ushort4v hi = *(const ushort4v*)&lds[row * QST + l16 * 8 + 4];
            ushort8 v8 = {lo.x, lo.y, lo.z, lo.w, hi.x, hi.y, hi.z, hi.w};
            *(ushort8*)(qbase + (size_t)(m0 + row) * E_ + nb0 + l16 * 8) = v8;
        }
    } else {
        // V epilogue: transpose 128x128 tile in LDS (two 64-dcol passes), coalesced stores.
        // p loop fully unrolled -> acc indices compile-time (rule #20).
        const int TST = 134;                   // padded stride (elems)
        int b2 = m0 >> 12;
        int s0 = m0 & 4095;
        #pragma unroll
        for (int p = 0; p < 2; ++p) {
            __syncthreads();                   // prior LDS use done
            #pragma unroll
            for (int gb = 0; gb < 2; ++gb) {
                int g = 2 * p + gb;
                int rid = wn * 32 + gb * 16 + l15;
                float bb = bias[nb0 + wn * 64 + g * 16 + l15];
                #pragma unroll
                for (int f = 0; f < 4; ++f) {
                    int sbase = wm * 64 + f * 16 + l4 * 4;
                    #pragma unroll
                    for (int r = 0; r < 4; ++r)
                        lds[rid * TST + sbase + r] = f2bf(acc[f][g][r] + bb);
                }
            }
            __syncthreads();
            int rid = t >> 2;
            int sc_ = (t & 3) * 32;
            int dcol = (rid >> 5) * 64 + (p * 2 + ((rid >> 4) & 1)) * 16 + (rid & 15);
            int gcol = nb0 + dcol;
            int hh = gcol >> 6, dd = gcol & 63;
            unsigned short* dst = vtg + ((size_t)(b2 * H_ + hh) * D_ + dd) * S_ + s0 + sc_;
            const unsigned short* srcl = lds + rid * TST + sc_;
            *(ushort8*)(dst)      = *(const ushort8*)(srcl);
            *(ushort8*)(dst + 8)  = *(const ushort8*)(srcl + 8);
            *(ushort8*)(dst + 16) = *(const ushort8*)(srcl + 16);
            *(ushort8*)(dst + 24) = *(const ushort8*)(srcl + 24);
        }
    }
}

// ---------------- banded flash attention: LDS-staged K + V^T, swapped QK^T, O^T PV ----------------
// scores arrive in log2 domain (Q pre-scaled by 0.125*log2e) -> exp2f softmax
__global__ __launch_bounds__(256) void attn(const unsigned short* __restrict__ qk,
        const unsigned short* __restrict__ vtg,
        const float* __restrict__ amask, float* __restrict__ out) {
    __shared__ unsigned short klds[2][2048];   // [buf] 32 rows x 64 cols, chunk-swizzled
    __shared__ unsigned short vlds[2][2048];   // [buf] V^T: 64 d-rows x 32 keys, chunk-swizzled
    __shared__ unsigned short plds[4][16 * 40];// per-wave P [16 q][32 keys], pad to 40
    __shared__ float fmlds[576];               // per-key additive mask (log2 units), block-constant

    // XCD-pinning: all 64 q-tiles of one (b,h) on one XCD
    int bid = blockIdx.x;
    int xcd = bid & 7;
    int j = bid >> 3;
    int qt = j & 63;
    int p_ = xcd + 8 * (j >> 6);
    int h = p_ % H_;
    int b = p_ / H_;

    int t = threadIdx.x, lane = t & 63, wv = t >> 6;
    int l15 = lane & 15, l4 = lane >> 4;
    const unsigned short* qp = qk;
    const unsigned short* kp = qk + (size_t)8192 * E_;
    size_t rowbase = (size_t)b * S_;
    int hcol = h * D_;
    const unsigned short* vth = vtg + (size_t)(b * H_ + h) * D_ * S_;
    const float* amb = amask + (size_t)b * S_;

    int q0 = qt * 64 + wv * 16;
    int myq = q0 + l15;
    bf16x8 qf[2];
    {
        const unsigned short* qrow = qp + (rowbase + myq) * E_ + hcol;
        qf[0] = *(const bf16x8*)(qrow + l4 * 8);
        qf[1] = *(const bf16x8*)(qrow + 32 + l4 * 8);
    }

    int kt0 = qt * 64 - 256;
    bool interior = (qt >= 4) && (qt <= 59);

    // --- per-key additive mask (log2 units), computed once
    for (int i = t; i < 576; i += 256) {
        int key = kt0 + i;
        float v = 0.f;
        if (key >= 0 && key < S_) v = (amb[key] != 0.f) ? -10000.f * L2E : 0.f;
        fmlds[i] = v;
    }

    // staging thread-constant decode
    int rK = t >> 3;                                   // K row 0..31
    int cK = (((t & 7) ^ (rK & 7)) << 3);              // swizzled chunk -> elem off
    const unsigned short* kbase_g = kp + rowbase * E_ + hcol + cK;
    int dV = t >> 2;                                   // V^T d-row 0..63
    int kcV = ((t & 3) ^ ((dV >> 1) & 3)) << 3;        // swizzled key chunk (2-way banks on read)
    const unsigned short* vbase_g = vth + (size_t)dV * S_;

    auto stage = [&](int bt, int buf) {
        int kg = kt0 + bt * 32;
        int kk = min(max(kg + rK, 0), S_ - 1);
        gl_lds16(kbase_g + (size_t)kk * E_, &klds[buf][wv * 512]);
        int vb = min(max(kg + kcV, 0), S_ - 8);        // kg multiple of 32 -> chunk all-in or all-out
        gl_lds16(vbase_g + vb, &vlds[buf][wv * 512]);
    };

    float mrun = -1e8f, lpart = 0.f;
    f32x4 oaccT[4];
    #pragma unroll
    for (int d4 = 0; d4 < 4; d4++) oaccT[d4] = (f32x4){0.f, 0.f, 0.f, 0.f};
    unsigned short* pl = (unsigned short*)plds[wv];

    stage(0, 0);

    int sV = ((l4 ^ ((l15 >> 1) & 3)) << 3);           // V read slot

    #pragma unroll 1
    for (int bt = 0; bt < 18; ++bt) {
        int buf = bt & 1;
        __syncthreads();                       // stage(bt) + fm fill landed; buf^1 free
        if (bt + 1 < 18) stage(bt + 1, buf ^ 1);
        int kg = kt0 + bt * 32;

        // --- additive mask from LDS (broadcast reads, conflict-free)
        int fo = bt * 32 + l4 * 4;
        float4 a4 = *(const float4*)&fmlds[fo];
        float4 b4 = *(const float4*)&fmlds[fo + 16];
        float fm[8] = {a4.x, a4.y, a4.z, a4.w, b4.x, b4.y, b4.z, b4.w};

        // --- K A-frags from swizzled LDS
        const unsigned short* kb = &klds[buf][l15 * 64];
        int c0 = ((l4 ^ (l15 & 7)) << 3);
        int c1 = (((4 + l4) ^ (l15 & 7)) << 3);
        bf16x8 kf00 = *(const bf16x8*)(kb + c0);
        bf16x8 kf01 = *(const bf16x8*)(kb + c1);
        bf16x8 kf10 = *(const bf16x8*)(kb + 1024 + c0);
        bf16x8 kf11 = *(const bf16x8*)(kb + 1024 + c1);

        // --- V^T A-frags (swizzled slots): vf[d4] = V^T[d4*16+l15][keys l4*8..+7]
        bf16x8 vf[4];
        #pragma unroll
        for (int d4 = 0; d4 < 4; d4++)
            vf[d4] = *(const bf16x8*)(&vlds[buf][(d4 * 16 + l15) * 32 + sV]);

        // --- swapped QK^T: st[nt][r] = S^T[key=kg+nt*16+l4*4+r][q=myq]  (log2 units)
        f32x4 z = (f32x4){0.f, 0.f, 0.f, 0.f};
        f32x4 st0 = __builtin_amdgcn_mfma_f32_16x16x32_bf16(kf00, qf[0], z, 0, 0, 0);
        st0 = __builtin_amdgcn_mfma_f32_16x16x32_bf16(kf01, qf[1], st0, 0, 0, 0);
        f32x4 st1 = __builtin_amdgcn_mfma_f32_16x16x32_bf16(kf10, qf[0], z, 0, 0, 0);
        st1 = __builtin_amdgcn_mfma_f32_16x16x32_bf16(kf11, qf[1], st1, 0, 0, 0);

        bool full = interior && (bt >= 1 + (wv >> 1)) && (bt <= 15 + (wv >> 1));
        float sv[8];
        if (full) {
            #pragma unroll
            for (int r = 0; r < 4; r++) { sv[r] = st0[r] + fm[r]; sv[4 + r] = st1[r] + fm[4 + r]; }
        } else {
            #pragma unroll
            for (int i = 0; i < 8; i++) {
                int key = kg + (i >> 2) * 16 + l4 * 4 + (i & 3);
                int dd = key - myq;
                bool valid = (key >= 0) && (key < S_) && (dd <= 256) && (dd >= -256);
                float s = (i < 4) ? st0[i & 3] : st1[i & 3];
                sv[i] = valid ? (s + fm[i]) : -1e30f;
            }
        }

        // --- defer-max online softmax (log2 domain)
        float mt = fmaxf(fmaxf(fmaxf(sv[0], sv[1]), fmaxf(sv[2], sv[3])),
                         fmaxf(fmaxf(sv[4], sv[5]), fmaxf(sv[6], sv[7])));
        if (__any(mt - mrun > 8.f)) {
            float mw = fmaxf(mt, __shfl_xor(mt, 16));
            mw = fmaxf(mw, __shfl_xor(mw, 32));
            float mnew = fmaxf(mrun, mw);
            float sc = exp2f(mrun - mnew);    // uniform over l4 for fixed l15=q
            mrun = mnew;
            lpart *= sc;
            #pragma unroll
            for (int d4 = 0; d4 < 4; d4++) {
                oaccT[d4][0] *= sc; oaccT[d4][1] *= sc; oaccT[d4][2] *= sc; oaccT[d4][3] *= sc;
            }
        }
        bf16x4 pb0, pb1;
        float ps = 0.f;
        #pragma unroll
        for (int r = 0; r < 4; r++) {
            float e0 = exp2f(sv[r] - mrun);
            float e1 = exp2f(sv[4 + r] - mrun);
            ps += e0 + e1;
            pb0[r] = (__bf16)e0;
            pb1[r] = (__bf16)e1;
        }
        lpart += ps;

        // --- P round-trip through per-wave LDS: P[q=l15][key]
        *(ushort4v*)(pl + l15 * 40 + l4 * 4)      = __builtin_bit_cast(ushort4v, pb0);
        *(ushort4v*)(pl + l15 * 40 + 16 + l4 * 4) = __builtin_bit_cast(ushort4v, pb1);
        asm volatile("s_waitcnt lgkmcnt(0)" ::: "memory");
        __builtin_amdgcn_sched_barrier(0);
        bf16x8 pf = *(const bf16x8*)(pl + l15 * 40 + l4 * 8);   // P^T B-frag

        // --- PV: O^T[d][q] += V^T x P^T
        #pragma unroll
        for (int d4 = 0; d4 < 4; d4++)
            oaccT[d4] = __builtin_amdgcn_mfma_f32_16x16x32_bf16(vf[d4], pf, oaccT[d4], 0, 0, 0);
    }

    // --- epilogue (all lane-local: q = l15)
    float lsum = lpart + __shfl_xor(lpart, 16);
    lsum += __shfl_xor(lsum, 32);
    float inv = 1.0f / lsum;
    if (amb[q0 + l15] < 0.f) inv = 0.f;
    float* orow = out + (rowbase + q0 + l15) * E_ + hcol;
    #pragma unroll
    for (int d4 = 0; d4 < 4; d4++) {
        float4 o4;
        o4.x = oaccT[d4][0] * inv;
        o4.y = oaccT[d4][1] * inv;
        o4.z = oaccT[d4][2] * inv;
        o4.w = oaccT[d4][3] * inv;
        *(float4*)(orow + d4 * 16 + l4 * 4) = o4;
    }
}

extern "C" void kernel_launch(void* const* d_in, const int* in_sizes, int n_in,
                              void* d_out, int out_size, void* d_ws, size_t ws_size,
                              hipStream_t stream) {
    const float* hs = (const float*)d_in[0];
    const float* am = (const float*)d_in[1];
    const float* Wq = (const float*)d_in[2];
    const float* bq = (const float*)d_in[3];
    const float* Wk = (const float*)d_in[4];
    const float* bk = (const float*)d_in[5];
    const float* Wv = (const float*)d_in[6];
    const float* bv = (const float*)d_in[7];
    float* out = (float*)d_out;
    unsigned short* xb  = (unsigned short*)d_ws;                  // 8192*768
    unsigned short* wtp = xb + (size_t)8192 * E_;                 // 3*768*768
    unsigned short* qkb = wtp + (size_t)3 * E_ * E_;              // 2*8192*768 (Q,K)
    unsigned short* vtg = qkb + (size_t)2 * 8192 * E_;            // 2*12*64*4096 (V^T)

    hipLaunchKernelGGL(cvt_x, dim3(2048), dim3(256), 0, stream, hs, xb, 8192 * E_ / 4);
    hipLaunchKernelGGL(cvt_w, dim3(24, 24, 3), dim3(32, 8), 0, stream, Wq, Wk, Wv, wtp);
    hipLaunchKernelGGL(qkv_gemm, dim3(1152), dim3(256), 0, stream, xb, wtp, bq, bk, bv, qkb, vtg);
    hipLaunchKernelGGL(attn, dim3(1536), dim3(256), 0, stream, qkb, vtg, am, out);
}